// Round 10
// baseline (303.130 us; speedup 1.0000x reference)
//
#include <hip/hip_runtime.h>
#include <hip/hip_bf16.h>
#include <math.h>

#define N_NODES 50000
#define N_EDGES 800000
#define HC 128
#define SLOT 64  // max in-degree slot; deg~Poisson(16), P(deg>64)~1e-13

#define BM 128
#define NBX ((N_NODES + BM - 1) / BM)        // 391 gemm blocks
#define NB_EDGE ((N_EDGES / 4 + 255) / 256)  // 782 edge blocks (4 edges/thread)

typedef short bh8 __attribute__((ext_vector_type(8)));  // 8 bf16 (4 VGPRs)
typedef float f4 __attribute__((ext_vector_type(4)));   // MFMA C/D
typedef float f2 __attribute__((ext_vector_type(2)));

__device__ __forceinline__ unsigned int pk2(float a, float b) {
  return (unsigned int)__bfloat16_as_ushort(__float2bfloat16(a)) |
         ((unsigned int)__bfloat16_as_ushort(__float2bfloat16(b)) << 16);
}

// ---------- K0: weight transpose+bf16 AND zero-init of cursor/stats ----------
// W[k][n] f32 -> Wt[m][n][k] bf16. Spare lanes zero cursor (ws is 0xAA-poisoned).
__global__ __launch_bounds__(256) void k_wprep(
    const float* __restrict__ Wl1, const float* __restrict__ Wr1,
    const float* __restrict__ Wl2, const float* __restrict__ Wr2,
    unsigned short* __restrict__ WtAll, int* __restrict__ cursor,
    float* __restrict__ chsum, float* __restrict__ chsq) {
  int gid = blockIdx.x * 256 + threadIdx.x;  // 0..65535
  int m = gid >> 14;
  int idx = gid & 16383;
  const float* src = (m == 0) ? Wl1 : (m == 1) ? Wr1 : (m == 2) ? Wl2 : Wr2;
  int k = idx >> 7, n = idx & 127;  // n fast -> coalesced reads
  WtAll[((size_t)m * HC + n) * HC + k] =
      __bfloat16_as_ushort(__float2bfloat16(src[k * HC + n]));
  if (gid < N_NODES) cursor[gid] = 0;
  if (gid < HC) { chsum[gid] = 0.f; chsq[gid] = 0.f; }
}

// ---------- shared GEMM tile body (both halves: Wl -> Y0, Wr -> Y1) ----------
// X staged through 32 KB swizzled LDS (bf16); B-fragments read DIRECTLY from
// global Wt (L2-resident 128 KB) — no Wls, so fused-kernel edge blocks keep
// high residency (R9 post-mortem: 64 KB LDS capped 2 blocks/CU, starved the
// atomic stream). LAYER2 applies BN+ELU while staging; F8 emits fp8-e4m3 Y0.
template <int LAYER2, int F8>
__device__ __forceinline__ void gemm_tile(
    int bx, const float* __restrict__ X, const unsigned short* __restrict__ Wt,
    const float* __restrict__ b0, const float* __restrict__ b1,
    void* __restrict__ Y0, float* __restrict__ Y1,
    const float* __restrict__ chsum, const float* __restrict__ chsq,
    const float* __restrict__ gamma, const float* __restrict__ beta) {
  __shared__ __align__(16) unsigned short Xls[128 * 128];  // 32 KB
  __shared__ float ssc[HC], ssh[HC];
  int tid = threadIdx.x;
  if (LAYER2) {
    if (tid < HC) {
      float mu = chsum[tid] * (1.f / N_NODES);
      float var = chsq[tid] * (1.f / N_NODES) - mu * mu;  // biased, jnp.var
      float sc = gamma[tid] * rsqrtf(var + 1e-5f);
      ssc[tid] = sc;
      ssh[tid] = beta[tid] - mu * sc;
    }
    __syncthreads();
  }
  int row0 = bx * BM;
  {  // stage X tile (fp32 -> bf16, 16B-granule XOR swizzle)
    int r = tid >> 1;
    int ks = (tid & 1) * 64;
    int gr = row0 + r;
    const float* xp = X + (size_t)gr * HC + ks;
    int sw = r & 15;
#pragma unroll
    for (int i = 0; i < 4; ++i) {
      float f[16];
      if (gr < N_NODES) {
        *(float4*)&f[0] = *(const float4*)(xp + i * 16);
        *(float4*)&f[4] = *(const float4*)(xp + i * 16 + 4);
        *(float4*)&f[8] = *(const float4*)(xp + i * 16 + 8);
        *(float4*)&f[12] = *(const float4*)(xp + i * 16 + 12);
      } else {
#pragma unroll
        for (int j = 0; j < 16; ++j) f[j] = 0.f;
      }
      if (LAYER2) {
#pragma unroll
        for (int j = 0; j < 16; ++j) {
          float y = fmaf(f[j], ssc[ks + i * 16 + j], ssh[ks + i * 16 + j]);
          f[j] = (y > 0.f) ? y : (__expf(y) - 1.f);  // elu
        }
      }
      int kg = (ks >> 3) + i * 2;
      *(uint4*)&Xls[r * 128 + ((kg ^ sw) * 8)] =
          make_uint4(pk2(f[0], f[1]), pk2(f[2], f[3]), pk2(f[4], f[5]), pk2(f[6], f[7]));
      *(uint4*)&Xls[r * 128 + (((kg + 1) ^ sw) * 8)] =
          make_uint4(pk2(f[8], f[9]), pk2(f[10], f[11]), pk2(f[12], f[13]), pk2(f[14], f[15]));
    }
  }
  __syncthreads();
  int lane = tid & 63;
  int wv = tid >> 6;
  int lrow = lane & 15;
  int lq = lane >> 4;
  int rbase = wv * 32;
  // A-fragments: load once from LDS, reuse across both halves
  bh8 afr[4][2];
#pragma unroll
  for (int kk = 0; kk < 4; ++kk) {
    int kg = kk * 4 + lq;
    afr[kk][0] = *(const bh8*)&Xls[(rbase + lrow) * 128 + ((kg ^ lrow) * 8)];
    afr[kk][1] = *(const bh8*)&Xls[(rbase + 16 + lrow) * 128 + ((kg ^ lrow) * 8)];
  }
#pragma unroll
  for (int half = 0; half < 2; ++half) {
    const unsigned short* wbase = Wt + half * (HC * HC);
    f4 acc[2][8];
#pragma unroll
    for (int mt = 0; mt < 2; ++mt)
#pragma unroll
      for (int nt = 0; nt < 8; ++nt) acc[mt][nt] = (f4){0.f, 0.f, 0.f, 0.f};
#pragma unroll
    for (int kk = 0; kk < 4; ++kk) {
      int kg = kk * 4 + lq;
      bh8 a0 = afr[kk][0];
      bh8 a1 = afr[kk][1];
#pragma unroll
      for (int nt = 0; nt < 8; ++nt) {
        bh8 b = *(const bh8*)(wbase + (nt * 16 + lrow) * HC + kg * 8);
        acc[0][nt] = __builtin_amdgcn_mfma_f32_16x16x32_bf16(a0, b, acc[0][nt], 0, 0, 0);
        acc[1][nt] = __builtin_amdgcn_mfma_f32_16x16x32_bf16(a1, b, acc[1][nt], 0, 0, 0);
      }
    }
    const float* bb = half ? b1 : b0;
    float bv[8];
#pragma unroll
    for (int nt = 0; nt < 8; ++nt) bv[nt] = bb[nt * 16 + lrow];
#pragma unroll
    for (int mt = 0; mt < 2; ++mt) {
#pragma unroll
      for (int rr = 0; rr < 4; ++rr) {
        int gr = row0 + rbase + mt * 16 + lq * 4 + rr;
        if (gr < N_NODES) {
          if (half == 0) {
            if (F8) {
#pragma unroll
              for (int nt = 0; nt < 8; ++nt) {
                float v = acc[mt][nt][rr] + bv[nt];
                int p = __builtin_amdgcn_cvt_pk_fp8_f32(v, v, 0, false);
                ((unsigned char*)Y0)[(size_t)gr * HC + nt * 16 + lrow] =
                    (unsigned char)(p & 0xff);
              }
            } else {
#pragma unroll
              for (int nt = 0; nt < 8; ++nt)
                ((unsigned short*)Y0)[(size_t)gr * HC + nt * 16 + lrow] =
                    __bfloat16_as_ushort(__float2bfloat16(acc[mt][nt][rr] + bv[nt]));
            }
          } else {
#pragma unroll
            for (int nt = 0; nt < 8; ++nt)
              Y1[(size_t)gr * HC + nt * 16 + lrow] = acc[mt][nt][rr] + bv[nt];
          }
        }
      }
    }
  }
}

// ---------- K1: fused [layer-1 GEMM] + [adjacency bucket build] ----------
// Blocks 0..NBX-1: gemm tiles. Blocks NBX+: 4 edges/thread with vectorized
// metadata loads and 4 independent atomics in flight (compensates the lower
// block residency of the fused kernel — R9 lesson).
__global__ __launch_bounds__(256) void k_g1prep(
    const float* __restrict__ X, const unsigned short* __restrict__ Wt,
    const float* __restrict__ b0, const float* __restrict__ b1,
    unsigned short* __restrict__ Y0b, float* __restrict__ Y1,
    const int* __restrict__ ei, const float* __restrict__ ew,
    int* __restrict__ cursor, unsigned int* __restrict__ slots) {
  int bid = blockIdx.x;
  if (bid < NBX) {
    gemm_tile<0, 0>(bid, X, Wt, b0, b1, (void*)Y0b, Y1, nullptr, nullptr,
                    nullptr, nullptr);
    return;
  }
  int e = ((bid - NBX) * 256 + threadIdx.x) * 4;
  if (e >= N_EDGES) return;
  int4 s4 = *(const int4*)(ei + e);
  int4 d4 = *(const int4*)(ei + N_EDGES + e);
  float4 w4 = *(const float4*)(ew + e);
  int ss[4] = {s4.x, s4.y, s4.z, s4.w};
  int dd[4] = {d4.x, d4.y, d4.z, d4.w};
  float ww[4] = {w4.x, w4.y, w4.z, w4.w};
  int pos[4];
#pragma unroll
  for (int i = 0; i < 4; ++i) pos[i] = atomicAdd(cursor + dd[i], 1);
#pragma unroll
  for (int i = 0; i < 4; ++i) {
    unsigned int wq = min((unsigned int)(ww[i] * 65536.f + 0.5f), 65535u);
    if (pos[i] < SLOT) {  // defensive; statistically never taken
      slots[(size_t)dd[i] * SLOT + pos[i]] = ((unsigned int)ss[i] << 16) | wq;
    }
  }
}

// ---------- K2: layer-2 GEMM (BN+ELU on staging; xl out as fp8) ----------
__global__ __launch_bounds__(256) void k_gemm2(
    const float* __restrict__ X, const unsigned short* __restrict__ Wt,
    const float* __restrict__ b0, const float* __restrict__ b1,
    unsigned char* __restrict__ Y0f8, float* __restrict__ Y1,
    const float* __restrict__ chsum, const float* __restrict__ chsq,
    const float* __restrict__ gamma, const float* __restrict__ beta) {
  gemm_tile<1, 1>(blockIdx.x, X, Wt, b0, b1, (void*)Y0f8, Y1, chsum, chsq,
                  gamma, beta);
}

// ---------- K3: fused attention + aggregation ----------
// 8 nodes/block; 32 lanes/node; lane owns 4 channels. First-32 edges
// cooperatively preloaded (1 packed uint/lane), broadcast via shfl.
// F8: xl rows are fp8 e4m3 (4 B/lane) else bf16 (8 B/lane).
template <int FINAL, int F8>
__global__ __launch_bounds__(256) void k_gat(
    const void* __restrict__ xlv, const float* __restrict__ xr,
    const int* __restrict__ cursor, const unsigned int* __restrict__ slots,
    const float* __restrict__ We, const float* __restrict__ att,
    const float* __restrict__ bias, float* __restrict__ out,
    const float* __restrict__ emb, const float* __restrict__ h1p,
    const float* __restrict__ chsum, const float* __restrict__ chsq,
    const float* __restrict__ gamma, const float* __restrict__ beta) {
  int g = threadIdx.x >> 5;
  int lane = threadIdx.x & 31;
  int n = blockIdx.x * 8 + g;
  int fi = n * 32 + lane;  // float4 index into [N,128]
  const uint2* xl2 = (const uint2*)xlv;               // bf16 rows
  const unsigned int* xf = (const unsigned int*)xlv;  // fp8 rows
  float4 xr4 = ((const float4*)xr)[fi];
  float4 we4 = ((const float4*)We)[lane];
  float4 at4 = ((const float4*)att)[lane];
  int deg = min(cursor[n], SLOT);
  int base = n * SLOT;
  int deg32 = min(deg, 32);

  unsigned int ev = (lane < deg32) ? slots[base + lane] : 0u;
  float evw = (float)(ev & 0xffffu) * (1.f / 65536.f);
  float wsum = evw;  // lanes >= deg32 contribute 0
#pragma unroll
  for (int m = 16; m >= 1; m >>= 1) wsum += __shfl_xor(wsum, m);

  float l = 0.f;
  float4 o = make_float4(0.f, 0.f, 0.f, 0.f);

  auto decode = [&](uint2 gc) -> float4 {
    float4 xlj;
    if (F8) {
      f2 ab = __builtin_amdgcn_cvt_pk_f32_fp8((int)gc.x, false);
      f2 cd = __builtin_amdgcn_cvt_pk_f32_fp8((int)gc.x, true);
      xlj.x = ab[0]; xlj.y = ab[1]; xlj.z = cd[0]; xlj.w = cd[1];
    } else {
      xlj.x = __uint_as_float(gc.x << 16);
      xlj.y = __uint_as_float(gc.x & 0xffff0000u);
      xlj.z = __uint_as_float(gc.y << 16);
      xlj.w = __uint_as_float(gc.y & 0xffff0000u);
    }
    return xlj;
  };
  auto edge_body = [&](float w, uint2 gc, bool valid) {
    float4 xlj = decode(gc);
    float4 v;
    v.x = fmaf(w, we4.x, xlj.x + xr4.x);
    v.y = fmaf(w, we4.y, xlj.y + xr4.y);
    v.z = fmaf(w, we4.z, xlj.z + xr4.z);
    v.w = fmaf(w, we4.w, xlj.w + xr4.w);
    v.x = fmaxf(v.x, 0.2f * v.x);  // leaky_relu
    v.y = fmaxf(v.y, 0.2f * v.y);
    v.z = fmaxf(v.z, 0.2f * v.z);
    v.w = fmaxf(v.w, 0.2f * v.w);
    float p = v.x * at4.x + v.y * at4.y + v.z * at4.z + v.w * at4.w;
    p += __shfl_xor(p, 1);
    p += __shfl_xor(p, 2);
    p += __shfl_xor(p, 4);              // 8-lane head group holds the logit
    float e = valid ? __expf(p) : 0.f;  // |p| bounded: no overflow, max-sub elided
    l += e;
    o.x = fmaf(e, xlj.x, o.x);
    o.y = fmaf(e, xlj.y, o.y);
    o.z = fmaf(e, xlj.z, o.z);
    o.w = fmaf(e, xlj.w, o.w);
  };
  auto fetch = [&](int j, uint2& qq, float& ww) {
    int jc = min(j, deg32 - 1);
    unsigned int evj = __shfl(ev, jc, 32);
    ww = (float)(evj & 0xffffu) * (1.f / 65536.f);
    int s = (int)(evj >> 16);
    if (F8) qq.x = xf[s * 32 + lane];
    else qq = xl2[s * 32 + lane];
  };

  if (deg32 > 0) {
    uint2 q0, q1, q2, q3;
    float w0, w1, w2, w3;
    fetch(0, q0, w0);
    fetch(1, q1, w1);
    fetch(2, q2, w2);
    fetch(3, q3, w3);
    for (int b = 0; b < deg32; b += 4) {
      uint2 c0 = q0, c1 = q1, c2 = q2, c3 = q3;
      float x0 = w0, x1 = w1, x2 = w2, x3 = w3;
      fetch(b + 4, q0, w0);
      fetch(b + 5, q1, w1);
      fetch(b + 6, q2, w2);
      fetch(b + 7, q3, w3);
      edge_body(x0, c0, true);
      edge_body(x1, c1, b + 1 < deg32);
      edge_body(x2, c2, b + 2 < deg32);
      edge_body(x3, c3, b + 3 < deg32);
    }
  }
  if (deg > 32) {  // rare tail (P ~ 1e-4 per node): direct loads
    for (int j = base + 32; j < base + deg; ++j) {
      unsigned int evj = slots[j];
      float w = (float)(evj & 0xffffu) * (1.f / 65536.f);
      wsum += w;
      int s = (int)(evj >> 16);
      uint2 gc;
      if (F8) gc.x = xf[s * 32 + lane];
      else gc = xl2[s * 32 + lane];
      edge_body(w, gc, true);
    }
  }
  {  // self-loop: attr = mean of incoming edge weights (0 if none)
    float wself = (deg > 0) ? wsum / (float)deg : 0.f;
    uint2 gs;
    if (F8) gs.x = xf[n * 32 + lane];
    else gs = xl2[n * 32 + lane];
    edge_body(wself, gs, true);
  }

  float inv = 1.f / l;
  float4 b4 = ((const float4*)bias)[lane];
  float4 r;
  r.x = fmaf(o.x, inv, b4.x);
  r.y = fmaf(o.y, inv, b4.y);
  r.z = fmaf(o.z, inv, b4.z);
  r.w = fmaf(o.w, inv, b4.w);
  if (FINAL) {
    float4 e4 = ((const float4*)emb)[fi];
    float4 h4 = ((const float4*)h1p)[fi];
    float4 cs = ((const float4*)chsum)[lane];
    float4 cq = ((const float4*)chsq)[lane];
    float4 gm = ((const float4*)gamma)[lane];
    float4 bt = ((const float4*)beta)[lane];
    const float invN = 1.f / N_NODES;
    float4 sc4, sh4;
    {
      float mu = cs.x * invN, var = cq.x * invN - mu * mu;
      sc4.x = gm.x * rsqrtf(var + 1e-5f); sh4.x = bt.x - mu * sc4.x;
      mu = cs.y * invN; var = cq.y * invN - mu * mu;
      sc4.y = gm.y * rsqrtf(var + 1e-5f); sh4.y = bt.y - mu * sc4.y;
      mu = cs.z * invN; var = cq.z * invN - mu * mu;
      sc4.z = gm.z * rsqrtf(var + 1e-5f); sh4.z = bt.z - mu * sc4.z;
      mu = cs.w * invN; var = cq.w * invN - mu * mu;
      sc4.w = gm.w * rsqrtf(var + 1e-5f); sh4.w = bt.w - mu * sc4.w;
    }
    float4 h;  // recompute BN+ELU of raw h1
    h.x = fmaf(h4.x, sc4.x, sh4.x);
    h.y = fmaf(h4.y, sc4.y, sh4.y);
    h.z = fmaf(h4.z, sc4.z, sh4.z);
    h.w = fmaf(h4.w, sc4.w, sh4.w);
    h.x = (h.x > 0.f) ? h.x : (__expf(h.x) - 1.f);
    h.y = (h.y > 0.f) ? h.y : (__expf(h.y) - 1.f);
    h.z = (h.z > 0.f) ? h.z : (__expf(h.z) - 1.f);
    h.w = (h.w > 0.f) ? h.w : (__expf(h.w) - 1.f);
    const float k3 = 1.f / 3.f;
    r.x = (e4.x + h.x + r.x) * k3;
    r.y = (e4.y + h.y + r.y) * k3;
    r.z = (e4.z + h.z + r.z) * k3;
    r.w = (e4.w + h.w + r.w) * k3;
  }
  ((float4*)out)[fi] = r;
}

// ---------- K4: BN stats (partial sums + per-channel atomics) ----------
#define BN_ROWS 200
__global__ __launch_bounds__(256) void k_bnstats(const float* __restrict__ h1,
                                                 float* __restrict__ chsum,
                                                 float* __restrict__ chsq) {
  int c = threadIdx.x & 127;
  int g = threadIdx.x >> 7;
  int r0 = blockIdx.x * BN_ROWS;
  float s = 0.f, q = 0.f;
  for (int r = r0 + g; r < r0 + BN_ROWS; r += 2) {
    float v = h1[(size_t)r * HC + c];
    s += v;
    q += v * v;
  }
  __shared__ float sh[256], shq[256];
  sh[threadIdx.x] = s;
  shq[threadIdx.x] = q;
  __syncthreads();
  if (g == 0) {
    atomicAdd(chsum + c, s + sh[threadIdx.x + 128]);
    atomicAdd(chsq + c, q + shq[threadIdx.x + 128]);
  }
}

extern "C" void kernel_launch(void* const* d_in, const int* in_sizes, int n_in,
                              void* d_out, int out_size, void* d_ws, size_t ws_size,
                              hipStream_t stream) {
  const float* emb = (const float*)d_in[0];
  const int* ei = (const int*)d_in[1];
  const float* ew = (const float*)d_in[2];
  const float* Wl1 = (const float*)d_in[3];
  const float* bl1 = (const float*)d_in[4];
  const float* Wr1 = (const float*)d_in[5];
  const float* br1 = (const float*)d_in[6];
  const float* We1 = (const float*)d_in[7];
  const float* att1 = (const float*)d_in[8];
  const float* bias1 = (const float*)d_in[9];
  const float* gamma1 = (const float*)d_in[10];
  const float* beta1 = (const float*)d_in[11];
  const float* Wl2 = (const float*)d_in[12];
  const float* bl2 = (const float*)d_in[13];
  const float* Wr2 = (const float*)d_in[14];
  const float* br2 = (const float*)d_in[15];
  const float* We2 = (const float*)d_in[16];
  const float* att2 = (const float*)d_in[17];
  const float* bias2 = (const float*)d_in[18];
  float* out = (float*)d_out;

  char* wsb = (char*)d_ws;
  size_t off = 0;
  auto alloc = [&](size_t bytes) -> void* {
    void* p = (void*)(wsb + off);
    off += (bytes + 255) & ~(size_t)255;
    return p;
  };
  int* cursor = (int*)alloc((size_t)N_NODES * 4);
  float* chsum = (float*)alloc(HC * 4);
  float* chsq = (float*)alloc(HC * 4);
  unsigned short* WtAll = (unsigned short*)alloc((size_t)4 * HC * HC * 2);  // 128 KB
  unsigned int* slots = (unsigned int*)alloc((size_t)N_NODES * SLOT * 4);   // 12.8 MB
  unsigned short* xlb = (unsigned short*)alloc((size_t)N_NODES * HC * 2);   // bf16 xl1
  unsigned char* xlf8 = (unsigned char*)alloc((size_t)N_NODES * HC);        // fp8 xl2
  float* xr = (float*)alloc((size_t)N_NODES * HC * 4);
  float* h1 = (float*)alloc((size_t)N_NODES * HC * 4);

  // K0 zeroes cursor/chsum/chsq in spare lanes (no memset dispatch needed)
  k_wprep<<<256, 256, 0, stream>>>(Wl1, Wr1, Wl2, Wr2, WtAll, cursor, chsum, chsq);
  // layer-1 GEMM overlapped with the atomic-wall bucket build
  k_g1prep<<<NBX + NB_EDGE, 256, 0, stream>>>(emb, WtAll, bl1, br1, xlb, xr,
                                              ei, ew, cursor, slots);
  k_gat<0, 0><<<N_NODES / 8, 256, 0, stream>>>(xlb, xr, cursor, slots, We1, att1,
                                               bias1, h1, nullptr, nullptr,
                                               nullptr, nullptr, nullptr, nullptr);
  k_bnstats<<<N_NODES / BN_ROWS, 256, 0, stream>>>(h1, chsum, chsq);
  // layer 2: GEMM computes BN scale/shift in-block + applies BN+ELU while
  // staging; emits xl as fp8. k_gat<1,1> fuses (emb + elu(bn(h1)) + h2)/3.
  k_gemm2<<<NBX, 256, 0, stream>>>(h1, WtAll + 2 * HC * HC, bl2, br2, xlf8, xr,
                                   chsum, chsq, gamma1, beta1);
  k_gat<1, 1><<<N_NODES / 8, 256, 0, stream>>>(xlf8, xr, cursor, slots, We2, att2,
                                               bias2, out, emb, h1, chsum, chsq,
                                               gamma1, beta1);
}

// Round 11
// 288.995 us; speedup vs baseline: 1.0489x; 1.0489x over previous
//
#include <hip/hip_runtime.h>
#include <hip/hip_bf16.h>
#include <math.h>

#define N_NODES 50000
#define N_EDGES 800000
#define HC 128
#define SLOT 64     // max in-degree slot; deg~Poisson(16), P(deg>64)~1e-13
#define CSTRIDE 16  // cursor padded: one counter per 64B L2 line (atomic theory R11)

#define BM 128
#define NBX ((N_NODES + BM - 1) / BM)        // 391 gemm blocks
#define NB_EDGE ((N_EDGES / 4 + 255) / 256)  // 782 edge blocks (4 edges/thread)

typedef short bh8 __attribute__((ext_vector_type(8)));  // 8 bf16 (4 VGPRs)
typedef float f4 __attribute__((ext_vector_type(4)));   // MFMA C/D
typedef float f2 __attribute__((ext_vector_type(2)));

__device__ __forceinline__ unsigned int pk2(float a, float b) {
  return (unsigned int)__bfloat16_as_ushort(__float2bfloat16(a)) |
         ((unsigned int)__bfloat16_as_ushort(__float2bfloat16(b)) << 16);
}
__device__ __forceinline__ float blo(unsigned int u) { return __uint_as_float(u << 16); }
__device__ __forceinline__ float bhi(unsigned int u) { return __uint_as_float(u & 0xffff0000u); }

// ---------- K0: weight transpose+bf16 AND zero-init (cursor/stats) ----------
__global__ __launch_bounds__(256) void k_wprep(
    const float* __restrict__ Wl1, const float* __restrict__ Wr1,
    const float* __restrict__ Wl2, const float* __restrict__ Wr2,
    unsigned short* __restrict__ WtAll, int* __restrict__ cursor,
    float* __restrict__ chsum, float* __restrict__ chsq) {
  int gid = blockIdx.x * 256 + threadIdx.x;  // 0..65535
  int m = gid >> 14;
  int idx = gid & 16383;
  const float* src = (m == 0) ? Wl1 : (m == 1) ? Wr1 : (m == 2) ? Wl2 : Wr2;
  int k = idx >> 7, n = idx & 127;  // n fast -> coalesced reads
  WtAll[((size_t)m * HC + n) * HC + k] =
      __bfloat16_as_ushort(__float2bfloat16(src[k * HC + n]));
  for (int i = gid; i < N_NODES * CSTRIDE; i += 65536) cursor[i] = 0;
  if (gid < HC) { chsum[gid] = 0.f; chsq[gid] = 0.f; }
}

// ---------- K1: fused [layer-1 GEMM, streaming-B] + [bucket build] ----------
// GEMM here is hidden behind the atomic wall, so B streams from L2 (keeps LDS
// at 32 KB -> edge blocks stay resident; R9/R10 lessons). Edge path: 4 edges
// per thread, cursor padded to 1/line to break L2 atomic line serialization.
__global__ __launch_bounds__(256) void k_g1prep(
    const float* __restrict__ X, const unsigned short* __restrict__ Wt,
    const float* __restrict__ b0, const float* __restrict__ b1,
    unsigned short* __restrict__ Y0b, float* __restrict__ Y1,
    const int* __restrict__ ei, const float* __restrict__ ew,
    int* __restrict__ cursor, unsigned int* __restrict__ slots) {
  int bid = blockIdx.x;
  int tid = threadIdx.x;
  if (bid >= NBX) {
    int e = ((bid - NBX) * 256 + tid) * 4;
    if (e >= N_EDGES) return;
    int4 s4 = *(const int4*)(ei + e);
    int4 d4 = *(const int4*)(ei + N_EDGES + e);
    float4 w4 = *(const float4*)(ew + e);
    int ss[4] = {s4.x, s4.y, s4.z, s4.w};
    int dd[4] = {d4.x, d4.y, d4.z, d4.w};
    float ww[4] = {w4.x, w4.y, w4.z, w4.w};
    int pos[4];
#pragma unroll
    for (int i = 0; i < 4; ++i) pos[i] = atomicAdd(cursor + dd[i] * CSTRIDE, 1);
#pragma unroll
    for (int i = 0; i < 4; ++i) {
      unsigned int wq = min((unsigned int)(ww[i] * 65536.f + 0.5f), 65535u);
      if (pos[i] < SLOT) {  // defensive; statistically never taken
        slots[(size_t)dd[i] * SLOT + pos[i]] = ((unsigned int)ss[i] << 16) | wq;
      }
    }
    return;
  }
  // ---- GEMM tile: X (fp32) staged to 32 KB swizzled bf16 LDS; B streamed ----
  __shared__ __align__(16) unsigned short Xls[128 * 128];  // 32 KB
  int row0 = bid * BM;
  {
    int r = tid >> 1;
    int ks = (tid & 1) * 64;
    int gr = row0 + r;
    const float* xp = X + (size_t)gr * HC + ks;
    int sw = r & 15;
#pragma unroll
    for (int i = 0; i < 4; ++i) {
      float f[16];
      if (gr < N_NODES) {
        *(float4*)&f[0] = *(const float4*)(xp + i * 16);
        *(float4*)&f[4] = *(const float4*)(xp + i * 16 + 4);
        *(float4*)&f[8] = *(const float4*)(xp + i * 16 + 8);
        *(float4*)&f[12] = *(const float4*)(xp + i * 16 + 12);
      } else {
#pragma unroll
        for (int j = 0; j < 16; ++j) f[j] = 0.f;
      }
      int kg = (ks >> 3) + i * 2;
      *(uint4*)&Xls[r * 128 + ((kg ^ sw) * 8)] =
          make_uint4(pk2(f[0], f[1]), pk2(f[2], f[3]), pk2(f[4], f[5]), pk2(f[6], f[7]));
      *(uint4*)&Xls[r * 128 + (((kg + 1) ^ sw) * 8)] =
          make_uint4(pk2(f[8], f[9]), pk2(f[10], f[11]), pk2(f[12], f[13]), pk2(f[14], f[15]));
    }
  }
  __syncthreads();
  int lane = tid & 63;
  int wv = tid >> 6;
  int lrow = lane & 15;
  int lq = lane >> 4;
  int rbase = wv * 32;
  bh8 afr[4][2];
#pragma unroll
  for (int kk = 0; kk < 4; ++kk) {
    int kg = kk * 4 + lq;
    afr[kk][0] = *(const bh8*)&Xls[(rbase + lrow) * 128 + ((kg ^ lrow) * 8)];
    afr[kk][1] = *(const bh8*)&Xls[(rbase + 16 + lrow) * 128 + ((kg ^ lrow) * 8)];
  }
#pragma unroll
  for (int half = 0; half < 2; ++half) {
    const unsigned short* wbase = Wt + half * (HC * HC);
    f4 acc[2][8];
#pragma unroll
    for (int mt = 0; mt < 2; ++mt)
#pragma unroll
      for (int nt = 0; nt < 8; ++nt) acc[mt][nt] = (f4){0.f, 0.f, 0.f, 0.f};
#pragma unroll
    for (int kk = 0; kk < 4; ++kk) {
      int kg = kk * 4 + lq;
#pragma unroll
      for (int nt = 0; nt < 8; ++nt) {
        bh8 b = *(const bh8*)(wbase + (nt * 16 + lrow) * HC + kg * 8);
        acc[0][nt] = __builtin_amdgcn_mfma_f32_16x16x32_bf16(afr[kk][0], b, acc[0][nt], 0, 0, 0);
        acc[1][nt] = __builtin_amdgcn_mfma_f32_16x16x32_bf16(afr[kk][1], b, acc[1][nt], 0, 0, 0);
      }
    }
    const float* bb = half ? b1 : b0;
    float bv[8];
#pragma unroll
    for (int nt = 0; nt < 8; ++nt) bv[nt] = bb[nt * 16 + lrow];
#pragma unroll
    for (int mt = 0; mt < 2; ++mt) {
#pragma unroll
      for (int rr = 0; rr < 4; ++rr) {
        int gr = row0 + rbase + mt * 16 + lq * 4 + rr;
        if (gr < N_NODES) {
          if (half == 0) {
#pragma unroll
            for (int nt = 0; nt < 8; ++nt)
              Y0b[(size_t)gr * HC + nt * 16 + lrow] =
                  __bfloat16_as_ushort(__float2bfloat16(acc[mt][nt][rr] + bv[nt]));
          } else {
#pragma unroll
            for (int nt = 0; nt < 8; ++nt)
              Y1[(size_t)gr * HC + nt * 16 + lrow] = acc[mt][nt][rr] + bv[nt];
          }
        }
      }
    }
  }
}

// ---------- K2: layer-2 GEMM — bf16 X in (BN+ELU on staging), LDS-staged W ----
// On the critical path: B through LDS (R10 regression: streaming-B here was
// latency-exposed). Emits xl as fp8-e4m3, xr as fp32.
__global__ __launch_bounds__(256) void k_gemm2(
    const unsigned short* __restrict__ Xb, const unsigned short* __restrict__ Wt,
    const float* __restrict__ b0, const float* __restrict__ b1,
    unsigned char* __restrict__ Y0f8, float* __restrict__ Y1,
    const float* __restrict__ chsum, const float* __restrict__ chsq,
    const float* __restrict__ gamma, const float* __restrict__ beta) {
  __shared__ __align__(16) unsigned short Xls[128 * 128];  // 32 KB
  __shared__ __align__(16) unsigned short Wls[128 * 128];  // 32 KB
  __shared__ float ssc[HC], ssh[HC];
  int tid = threadIdx.x;
  if (tid < HC) {
    float mu = chsum[tid] * (1.f / N_NODES);
    float var = chsq[tid] * (1.f / N_NODES) - mu * mu;  // biased, jnp.var
    float sc = gamma[tid] * rsqrtf(var + 1e-5f);
    ssc[tid] = sc;
    ssh[tid] = beta[tid] - mu * sc;
  }
  __syncthreads();
  int row0 = blockIdx.x * BM;
  {  // stage X tile: decode bf16 -> BN+ELU -> bf16, swizzled
    int r = tid >> 1;
    int ks = (tid & 1) * 64;
    int gr = row0 + r;
    const unsigned short* xp = Xb + (size_t)gr * HC + ks;
    int sw = r & 15;
#pragma unroll
    for (int i = 0; i < 4; ++i) {
      float f[16];
      if (gr < N_NODES) {
        uint4 ua = *(const uint4*)(xp + i * 16);
        uint4 ub = *(const uint4*)(xp + i * 16 + 8);
        f[0] = blo(ua.x); f[1] = bhi(ua.x); f[2] = blo(ua.y); f[3] = bhi(ua.y);
        f[4] = blo(ua.z); f[5] = bhi(ua.z); f[6] = blo(ua.w); f[7] = bhi(ua.w);
        f[8] = blo(ub.x); f[9] = bhi(ub.x); f[10] = blo(ub.y); f[11] = bhi(ub.y);
        f[12] = blo(ub.z); f[13] = bhi(ub.z); f[14] = blo(ub.w); f[15] = bhi(ub.w);
      } else {
#pragma unroll
        for (int j = 0; j < 16; ++j) f[j] = 0.f;
      }
#pragma unroll
      for (int j = 0; j < 16; ++j) {
        float y = fmaf(f[j], ssc[ks + i * 16 + j], ssh[ks + i * 16 + j]);
        f[j] = (y > 0.f) ? y : (__expf(y) - 1.f);  // elu
      }
      int kg = (ks >> 3) + i * 2;
      *(uint4*)&Xls[r * 128 + ((kg ^ sw) * 8)] =
          make_uint4(pk2(f[0], f[1]), pk2(f[2], f[3]), pk2(f[4], f[5]), pk2(f[6], f[7]));
      *(uint4*)&Xls[r * 128 + (((kg + 1) ^ sw) * 8)] =
          make_uint4(pk2(f[8], f[9]), pk2(f[10], f[11]), pk2(f[12], f[13]), pk2(f[14], f[15]));
    }
  }
  int lane = tid & 63;
  int wv = tid >> 6;
  int lrow = lane & 15;
  int lq = lane >> 4;
  int rbase = wv * 32;
#pragma unroll
  for (int half = 0; half < 2; ++half) {
    if (half) __syncthreads();  // all waves done reading Wls(half0)
    {
      int n = tid >> 1;
      int ks = (tid & 1) * 64;
      const unsigned short* wp = Wt + half * (HC * HC) + n * HC + ks;
      int swn = n & 15;
#pragma unroll
      for (int g = 0; g < 8; ++g) {
        uint4 v = *(const uint4*)(wp + g * 8);
        int kg = (ks >> 3) + g;
        *(uint4*)&Wls[n * 128 + ((kg ^ swn) * 8)] = v;
      }
    }
    __syncthreads();  // also covers Xls staging for half 0
    f4 acc[2][8];
#pragma unroll
    for (int mt = 0; mt < 2; ++mt)
#pragma unroll
      for (int nt = 0; nt < 8; ++nt) acc[mt][nt] = (f4){0.f, 0.f, 0.f, 0.f};
#pragma unroll
    for (int kk = 0; kk < 4; ++kk) {
      int kg = kk * 4 + lq;
      bh8 a0 = *(const bh8*)&Xls[(rbase + lrow) * 128 + ((kg ^ lrow) * 8)];
      bh8 a1 = *(const bh8*)&Xls[(rbase + 16 + lrow) * 128 + ((kg ^ lrow) * 8)];
#pragma unroll
      for (int nt = 0; nt < 8; ++nt) {
        bh8 b = *(const bh8*)&Wls[(nt * 16 + lrow) * 128 + ((kg ^ lrow) * 8)];
        acc[0][nt] = __builtin_amdgcn_mfma_f32_16x16x32_bf16(a0, b, acc[0][nt], 0, 0, 0);
        acc[1][nt] = __builtin_amdgcn_mfma_f32_16x16x32_bf16(a1, b, acc[1][nt], 0, 0, 0);
      }
    }
    const float* bb = half ? b1 : b0;
    float bv[8];
#pragma unroll
    for (int nt = 0; nt < 8; ++nt) bv[nt] = bb[nt * 16 + lrow];
#pragma unroll
    for (int mt = 0; mt < 2; ++mt) {
#pragma unroll
      for (int rr = 0; rr < 4; ++rr) {
        int gr = row0 + rbase + mt * 16 + lq * 4 + rr;
        if (gr < N_NODES) {
          if (half == 0) {
#pragma unroll
            for (int nt = 0; nt < 8; ++nt) {
              float v = acc[mt][nt][rr] + bv[nt];
              int p = __builtin_amdgcn_cvt_pk_fp8_f32(v, v, 0, false);
              Y0f8[(size_t)gr * HC + nt * 16 + lrow] = (unsigned char)(p & 0xff);
            }
          } else {
#pragma unroll
            for (int nt = 0; nt < 8; ++nt)
              Y1[(size_t)gr * HC + nt * 16 + lrow] = acc[mt][nt][rr] + bv[nt];
          }
        }
      }
    }
  }
}

// ---------- K3: fused attention + aggregation ----------
// 8 nodes/block; 32 lanes/node; lane owns 4 channels. First-32 edges
// cooperatively preloaded (1 packed uint/lane), broadcast via shfl.
// FINAL=0: xl bf16, out bf16 (h1). FINAL=1: xl fp8, out fp32 + fusion.
template <int FINAL, int F8>
__global__ __launch_bounds__(256) void k_gat(
    const void* __restrict__ xlv, const float* __restrict__ xr,
    const int* __restrict__ cursor, const unsigned int* __restrict__ slots,
    const float* __restrict__ We, const float* __restrict__ att,
    const float* __restrict__ bias, void* __restrict__ out,
    const float* __restrict__ emb, const unsigned short* __restrict__ h1p,
    const float* __restrict__ chsum, const float* __restrict__ chsq,
    const float* __restrict__ gamma, const float* __restrict__ beta) {
  int g = threadIdx.x >> 5;
  int lane = threadIdx.x & 31;
  int n = blockIdx.x * 8 + g;
  int fi = n * 32 + lane;  // float4/uint2 index into [N,128]
  const uint2* xl2 = (const uint2*)xlv;               // bf16 rows
  const unsigned int* xf = (const unsigned int*)xlv;  // fp8 rows
  float4 xr4 = ((const float4*)xr)[fi];
  float4 we4 = ((const float4*)We)[lane];
  float4 at4 = ((const float4*)att)[lane];
  int deg = min(cursor[n * CSTRIDE], SLOT);
  int base = n * SLOT;
  int deg32 = min(deg, 32);

  unsigned int ev = (lane < deg32) ? slots[base + lane] : 0u;
  float evw = (float)(ev & 0xffffu) * (1.f / 65536.f);
  float wsum = evw;  // lanes >= deg32 contribute 0
#pragma unroll
  for (int m = 16; m >= 1; m >>= 1) wsum += __shfl_xor(wsum, m);

  float l = 0.f;
  float4 o = make_float4(0.f, 0.f, 0.f, 0.f);

  auto decode = [&](uint2 gc) -> float4 {
    float4 xlj;
    if (F8) {
      f2 ab = __builtin_amdgcn_cvt_pk_f32_fp8((int)gc.x, false);
      f2 cd = __builtin_amdgcn_cvt_pk_f32_fp8((int)gc.x, true);
      xlj.x = ab[0]; xlj.y = ab[1]; xlj.z = cd[0]; xlj.w = cd[1];
    } else {
      xlj.x = blo(gc.x); xlj.y = bhi(gc.x);
      xlj.z = blo(gc.y); xlj.w = bhi(gc.y);
    }
    return xlj;
  };
  auto edge_body = [&](float w, uint2 gc, bool valid) {
    float4 xlj = decode(gc);
    float4 v;
    v.x = fmaf(w, we4.x, xlj.x + xr4.x);
    v.y = fmaf(w, we4.y, xlj.y + xr4.y);
    v.z = fmaf(w, we4.z, xlj.z + xr4.z);
    v.w = fmaf(w, we4.w, xlj.w + xr4.w);
    v.x = fmaxf(v.x, 0.2f * v.x);  // leaky_relu
    v.y = fmaxf(v.y, 0.2f * v.y);
    v.z = fmaxf(v.z, 0.2f * v.z);
    v.w = fmaxf(v.w, 0.2f * v.w);
    float p = v.x * at4.x + v.y * at4.y + v.z * at4.z + v.w * at4.w;
    p += __shfl_xor(p, 1);
    p += __shfl_xor(p, 2);
    p += __shfl_xor(p, 4);              // 8-lane head group holds the logit
    float e = valid ? __expf(p) : 0.f;  // |p| bounded: no overflow, max-sub elided
    l += e;
    o.x = fmaf(e, xlj.x, o.x);
    o.y = fmaf(e, xlj.y, o.y);
    o.z = fmaf(e, xlj.z, o.z);
    o.w = fmaf(e, xlj.w, o.w);
  };
  auto fetch = [&](int j, uint2& qq, float& ww) {
    int jc = min(j, deg32 - 1);
    unsigned int evj = __shfl(ev, jc, 32);
    ww = (float)(evj & 0xffffu) * (1.f / 65536.f);
    int s = (int)(evj >> 16);
    if (F8) qq.x = xf[s * 32 + lane];
    else qq = xl2[s * 32 + lane];
  };

  if (deg32 > 0) {
    uint2 q0, q1, q2, q3;
    float w0, w1, w2, w3;
    fetch(0, q0, w0);
    fetch(1, q1, w1);
    fetch(2, q2, w2);
    fetch(3, q3, w3);
    for (int b = 0; b < deg32; b += 4) {
      uint2 c0 = q0, c1 = q1, c2 = q2, c3 = q3;
      float x0 = w0, x1 = w1, x2 = w2, x3 = w3;
      fetch(b + 4, q0, w0);
      fetch(b + 5, q1, w1);
      fetch(b + 6, q2, w2);
      fetch(b + 7, q3, w3);
      edge_body(x0, c0, true);
      edge_body(x1, c1, b + 1 < deg32);
      edge_body(x2, c2, b + 2 < deg32);
      edge_body(x3, c3, b + 3 < deg32);
    }
  }
  if (deg > 32) {  // rare tail (P ~ 1e-4 per node): direct loads
    for (int j = base + 32; j < base + deg; ++j) {
      unsigned int evj = slots[j];
      float w = (float)(evj & 0xffffu) * (1.f / 65536.f);
      wsum += w;
      int s = (int)(evj >> 16);
      uint2 gc;
      if (F8) gc.x = xf[s * 32 + lane];
      else gc = xl2[s * 32 + lane];
      edge_body(w, gc, true);
    }
  }
  {  // self-loop: attr = mean of incoming edge weights (0 if none)
    float wself = (deg > 0) ? wsum / (float)deg : 0.f;
    uint2 gs;
    if (F8) gs.x = xf[n * 32 + lane];
    else gs = xl2[n * 32 + lane];
    edge_body(wself, gs, true);
  }

  float inv = 1.f / l;
  float4 b4 = ((const float4*)bias)[lane];
  float4 r;
  r.x = fmaf(o.x, inv, b4.x);
  r.y = fmaf(o.y, inv, b4.y);
  r.z = fmaf(o.z, inv, b4.z);
  r.w = fmaf(o.w, inv, b4.w);
  if (FINAL) {
    float4 e4 = ((const float4*)emb)[fi];
    uint2 hh = ((const uint2*)h1p)[fi];
    float4 h4;
    h4.x = blo(hh.x); h4.y = bhi(hh.x); h4.z = blo(hh.y); h4.w = bhi(hh.y);
    float4 cs = ((const float4*)chsum)[lane];
    float4 cq = ((const float4*)chsq)[lane];
    float4 gm = ((const float4*)gamma)[lane];
    float4 bt = ((const float4*)beta)[lane];
    const float invN = 1.f / N_NODES;
    float4 sc4, sh4;
    {
      float mu = cs.x * invN, var = cq.x * invN - mu * mu;
      sc4.x = gm.x * rsqrtf(var + 1e-5f); sh4.x = bt.x - mu * sc4.x;
      mu = cs.y * invN; var = cq.y * invN - mu * mu;
      sc4.y = gm.y * rsqrtf(var + 1e-5f); sh4.y = bt.y - mu * sc4.y;
      mu = cs.z * invN; var = cq.z * invN - mu * mu;
      sc4.z = gm.z * rsqrtf(var + 1e-5f); sh4.z = bt.z - mu * sc4.z;
      mu = cs.w * invN; var = cq.w * invN - mu * mu;
      sc4.w = gm.w * rsqrtf(var + 1e-5f); sh4.w = bt.w - mu * sc4.w;
    }
    float4 h;  // recompute BN+ELU of bf16 h1 (consistent with gemm2's input)
    h.x = fmaf(h4.x, sc4.x, sh4.x);
    h.y = fmaf(h4.y, sc4.y, sh4.y);
    h.z = fmaf(h4.z, sc4.z, sh4.z);
    h.w = fmaf(h4.w, sc4.w, sh4.w);
    h.x = (h.x > 0.f) ? h.x : (__expf(h.x) - 1.f);
    h.y = (h.y > 0.f) ? h.y : (__expf(h.y) - 1.f);
    h.z = (h.z > 0.f) ? h.z : (__expf(h.z) - 1.f);
    h.w = (h.w > 0.f) ? h.w : (__expf(h.w) - 1.f);
    const float k3 = 1.f / 3.f;
    r.x = (e4.x + h.x + r.x) * k3;
    r.y = (e4.y + h.y + r.y) * k3;
    r.z = (e4.z + h.z + r.z) * k3;
    r.w = (e4.w + h.w + r.w) * k3;
    ((float4*)out)[fi] = r;
  } else {
    ((uint2*)out)[fi] = make_uint2(pk2(r.x, r.y), pk2(r.z, r.w));  // h1 bf16
  }
}

// ---------- K4: BN stats over bf16 h1 (uint pair loads + per-channel atomics) --
#define BN_ROWS 200
__global__ __launch_bounds__(256) void k_bnstats(const unsigned short* __restrict__ h1b,
                                                 float* __restrict__ chsum,
                                                 float* __restrict__ chsq) {
  int c2 = threadIdx.x & 63;  // channel pair (2*c2, 2*c2+1)
  int g = threadIdx.x >> 6;   // 0..3
  int r0 = blockIdx.x * BN_ROWS;
  float s0 = 0.f, s1 = 0.f, q0 = 0.f, q1 = 0.f;
  const unsigned int* h32 = (const unsigned int*)h1b;
  for (int r = r0 + g; r < r0 + BN_ROWS; r += 4) {
    unsigned int u = h32[(size_t)r * 64 + c2];
    float a = blo(u), b = bhi(u);
    s0 += a; q0 += a * a;
    s1 += b; q1 += b * b;
  }
  __shared__ float sh[256][4];
  sh[threadIdx.x][0] = s0; sh[threadIdx.x][1] = q0;
  sh[threadIdx.x][2] = s1; sh[threadIdx.x][3] = q1;
  __syncthreads();
  if (g == 0) {
    float ts0 = 0.f, tq0 = 0.f, ts1 = 0.f, tq1 = 0.f;
#pragma unroll
    for (int gg = 0; gg < 4; ++gg) {
      ts0 += sh[gg * 64 + c2][0]; tq0 += sh[gg * 64 + c2][1];
      ts1 += sh[gg * 64 + c2][2]; tq1 += sh[gg * 64 + c2][3];
    }
    atomicAdd(chsum + 2 * c2, ts0);
    atomicAdd(chsq + 2 * c2, tq0);
    atomicAdd(chsum + 2 * c2 + 1, ts1);
    atomicAdd(chsq + 2 * c2 + 1, tq1);
  }
}

extern "C" void kernel_launch(void* const* d_in, const int* in_sizes, int n_in,
                              void* d_out, int out_size, void* d_ws, size_t ws_size,
                              hipStream_t stream) {
  const float* emb = (const float*)d_in[0];
  const int* ei = (const int*)d_in[1];
  const float* ew = (const float*)d_in[2];
  const float* Wl1 = (const float*)d_in[3];
  const float* bl1 = (const float*)d_in[4];
  const float* Wr1 = (const float*)d_in[5];
  const float* br1 = (const float*)d_in[6];
  const float* We1 = (const float*)d_in[7];
  const float* att1 = (const float*)d_in[8];
  const float* bias1 = (const float*)d_in[9];
  const float* gamma1 = (const float*)d_in[10];
  const float* beta1 = (const float*)d_in[11];
  const float* Wl2 = (const float*)d_in[12];
  const float* bl2 = (const float*)d_in[13];
  const float* Wr2 = (const float*)d_in[14];
  const float* br2 = (const float*)d_in[15];
  const float* We2 = (const float*)d_in[16];
  const float* att2 = (const float*)d_in[17];
  const float* bias2 = (const float*)d_in[18];
  float* out = (float*)d_out;

  char* wsb = (char*)d_ws;
  size_t off = 0;
  auto alloc = [&](size_t bytes) -> void* {
    void* p = (void*)(wsb + off);
    off += (bytes + 255) & ~(size_t)255;
    return p;
  };
  int* cursor = (int*)alloc((size_t)N_NODES * CSTRIDE * 4);  // 3.2 MB padded
  float* chsum = (float*)alloc(HC * 4);
  float* chsq = (float*)alloc(HC * 4);
  unsigned short* WtAll = (unsigned short*)alloc((size_t)4 * HC * HC * 2);  // 128 KB
  unsigned int* slots = (unsigned int*)alloc((size_t)N_NODES * SLOT * 4);   // 12.8 MB
  unsigned short* xlb = (unsigned short*)alloc((size_t)N_NODES * HC * 2);   // bf16 xl1
  unsigned char* xlf8 = (unsigned char*)alloc((size_t)N_NODES * HC);        // fp8 xl2
  float* xr = (float*)alloc((size_t)N_NODES * HC * 4);
  unsigned short* h1b = (unsigned short*)alloc((size_t)N_NODES * HC * 2);   // bf16 h1

  // K0 zeroes cursor/chsum/chsq in spare lanes (no memset dispatch needed)
  k_wprep<<<256, 256, 0, stream>>>(Wl1, Wr1, Wl2, Wr2, WtAll, cursor, chsum, chsq);
  // layer-1 GEMM overlapped with the atomic-wall bucket build
  k_g1prep<<<NBX + NB_EDGE, 256, 0, stream>>>(emb, WtAll, bl1, br1, xlb, xr,
                                              ei, ew, cursor, slots);
  k_gat<0, 0><<<N_NODES / 8, 256, 0, stream>>>(xlb, xr, cursor, slots, We1, att1,
                                               bias1, (void*)h1b, nullptr, nullptr,
                                               nullptr, nullptr, nullptr, nullptr);
  k_bnstats<<<N_NODES / BN_ROWS, 256, 0, stream>>>(h1b, chsum, chsq);
  // layer 2: GEMM computes BN scale/shift + applies BN+ELU while staging;
  // emits xl as fp8. k_gat<1,1> fuses (emb + elu(bn(h1)) + h2)/3.
  k_gemm2<<<NBX, 256, 0, stream>>>(h1b, WtAll + 2 * HC * HC, bl2, br2, xlf8, xr,
                                   chsum, chsq, gamma1, beta1);
  k_gat<1, 1><<<N_NODES / 8, 256, 0, stream>>>(xlf8, xr, cursor, slots, We2, att2,
                                               bias2, (void*)out, emb, h1b,
                                               chsum, chsq, gamma1, beta1);
}